// Round 5
// baseline (78.757 us; speedup 1.0000x reference)
//
#include <hip/hip_runtime.h>
#include <float.h>

// EuclideanCodebook R5: 8-wave 8-phase-style schedule (T3+T4+T5 port).
// 32x32x16 f16-split MFMA (3 passes -> 4 fused accumulators), A(x) in regs,
// B(codebook) pre-arranged in exact fragment order (conflict-free ds_read_b128,
// linear global_load_lds). 256 blocks x 512 thr (1/CU), CH=64 dbuf, per-chunk:
// vmcnt(0)+barrier, then 4 sub-phases {8 ds_read; barrier; setprio1; 12 MFMA;
// setprio0; barrier}, DMA for chunk+1 issued in phase 0.
// score = 2*dot - e^2 (x^2 dropped: per-row constant, argmax-invariant).

#define Cdim        128
#define KCODES      1024
#define CH          64
#define NCH         16
#define BROWS       256       // 8 waves x 32 rows
#define THREADS     512
#define FRAG_OFF    4096      // ws: [esq 4KB | frag image 512KB]
#define CHUNK_BYTES 32768     // per chunk: hi 16KB + lo 16KB

typedef _Float16 f16;
typedef __attribute__((ext_vector_type(8)))  _Float16 f16x8;
typedef __attribute__((ext_vector_type(16))) float    f32x16;

// ---------------- e_sq pre-pass (exact fp32) ----------------
__global__ __launch_bounds__(256) void esq_kernel(const float* __restrict__ embed,
                                                  float* __restrict__ esq, int K) {
    int gid  = blockIdx.x * blockDim.x + threadIdx.x;
    int code = gid >> 6;
    int lane = threadIdx.x & 63;
    if (code >= K) return;
    float2 v = ((const float2*)(embed + (size_t)code * Cdim))[lane];
    float  s = fmaf(v.x, v.x, v.y * v.y);
    #pragma unroll
    for (int m = 32; m >= 1; m >>= 1) s += __shfl_xor(s, m, 64);
    if (lane == 0) esq[code] = s;
}

__device__ __forceinline__ void cvt8(float4 a, float4 b, f16x8& h, f16x8& lo) {
    float v[8] = {a.x, a.y, a.z, a.w, b.x, b.y, b.z, b.w};
    #pragma unroll
    for (int i = 0; i < 8; ++i) {
        f16 hh = (f16)v[i];
        h[i]  = hh;
        lo[i] = (f16)(v[i] - (float)hh);
    }
}

// ---- codebook -> f16 hi/lo image in EXACT fragment order ----
// lane (lh,lm) reading frag (n,kk) wants e[n*32+lm][kk*16+lh*8 .. +8]
// at chunk_base + ((n*8+kk)*2+lh)*512 + lm*16  (hi; lo at +16KB).
__global__ __launch_bounds__(256) void bconv_kernel(const float* __restrict__ embed,
                                                    char* __restrict__ img) {
    int t    = blockIdx.x * 256 + threadIdx.x;   // 16384 threads total
    int code = t >> 4;
    int seg  = t & 15;
    int kk   = seg >> 1;
    int lh   = seg & 1;
    const float4* p = (const float4*)(embed + (size_t)code * Cdim + kk * 16 + lh * 8);
    float4 v0 = p[0], v1 = p[1];
    f16x8 h, lo;
    cvt8(v0, v1, h, lo);
    int ch = code >> 6, n = (code >> 5) & 1, lm = code & 31;
    size_t base = FRAG_OFF + (size_t)ch * CHUNK_BYTES
                + (size_t)(((n * 8 + kk) * 2 + lh) * 512 + lm * 16);
    *(f16x8*)(img + base)         = h;
    *(f16x8*)(img + base + 16384) = lo;
}

// ---------------- async global->LDS 16B ----------------
__device__ __forceinline__ void gll16(const void* g, void* l) {
    __builtin_amdgcn_global_load_lds(
        (const __attribute__((address_space(1))) unsigned int*)g,
        (__attribute__((address_space(3))) unsigned int*)l, 16, 0, 0);
}

__global__ __launch_bounds__(THREADS, 2) void vq_kernel(
    const float* __restrict__ x, const float* __restrict__ embed,
    const char* __restrict__ ws, float* __restrict__ outq,
    float* __restrict__ outi) {

    __shared__ __align__(16) char  Bb[2][CHUNK_BYTES];   // 64KB dbuf
    __shared__ __align__(16) float esq_lds[KCODES];      // 4KB
    __shared__ int winners[BROWS];

    const int tid  = threadIdx.x;
    const int wid  = tid >> 6;        // wave 0..7, owns rows wid*32..+31
    const int l    = tid & 63;
    const int lm   = l & 31;
    const int lh   = l >> 5;
    const int row0 = blockIdx.x * BROWS;

    const char* frag = ws + FRAG_OFF;

    // ---- prologue DMA: chunk 0 (4KB per wave) + esq ----
    {
        const char* src = frag + wid * 4096 + (size_t)l * 16;
        char*       dst = &Bb[0][wid * 4096];
        #pragma unroll
        for (int i = 0; i < 4; ++i) gll16(src + i * 1024, dst + i * 1024);
        if (wid < 4)
            gll16(ws + wid * 1024 + (size_t)l * 16, (char*)esq_lds + wid * 1024);
    }

    // ---- x rows -> f16 hi/lo register fragments (hides chunk-0 DMA) ----
    f16x8 ah[8], al[8];
    {
        const float* xr = x + (size_t)(row0 + wid * 32 + lm) * Cdim + lh * 8;
        #pragma unroll
        for (int kk = 0; kk < 8; ++kk) {
            float4 v0 = *(const float4*)(xr + kk * 16);
            float4 v1 = *(const float4*)(xr + kk * 16 + 4);
            cvt8(v0, v1, ah[kk], al[kk]);
        }
    }

    float best[16]; int bidx[16];
    #pragma unroll
    for (int r = 0; r < 16; ++r) { best[r] = -FLT_MAX; bidx[r] = 0; }

    #pragma unroll 1
    for (int ch = 0; ch < NCH; ++ch) {
        const int cur = ch & 1, nxt = cur ^ 1;

        asm volatile("s_waitcnt vmcnt(0)" ::: "memory");  // own chunk-ch loads done
        __builtin_amdgcn_s_barrier();                     // => all waves' loads done

        const float eq0 = esq_lds[ch * CH + lm];
        const float eq1 = esq_lds[ch * CH + 32 + lm];

        f32x16 a0, a1, a2, a3;
        #pragma unroll
        for (int r = 0; r < 16; ++r) { a0[r] = 0.f; a1[r] = 0.f; a2[r] = 0.f; a3[r] = 0.f; }

        const char* bb = &Bb[cur][(size_t)l * 16];

        #pragma unroll
        for (int p = 0; p < 4; ++p) {
            if (p == 0 && ch + 1 < NCH) {   // prefetch chunk ch+1 (3 phases in flight)
                const char* src = frag + (size_t)(ch + 1) * CHUNK_BYTES
                                + wid * 4096 + (size_t)l * 16;
                char* dst = &Bb[nxt][wid * 4096];
                #pragma unroll
                for (int i = 0; i < 4; ++i) gll16(src + i * 1024, dst + i * 1024);
            }
            const int k0 = 2 * p, k1 = 2 * p + 1;
            // async ds_reads for this phase's two k-steps
            f16x8 bh0a = *(const f16x8*)(bb + k0 * 1024);
            f16x8 bh1a = *(const f16x8*)(bb + 8192  + k0 * 1024);
            f16x8 bl0a = *(const f16x8*)(bb + 16384 + k0 * 1024);
            f16x8 bl1a = *(const f16x8*)(bb + 24576 + k0 * 1024);
            f16x8 bh0b = *(const f16x8*)(bb + k1 * 1024);
            f16x8 bh1b = *(const f16x8*)(bb + 8192  + k1 * 1024);
            f16x8 bl0b = *(const f16x8*)(bb + 16384 + k1 * 1024);
            f16x8 bl1b = *(const f16x8*)(bb + 24576 + k1 * 1024);

            __builtin_amdgcn_s_barrier();
            __builtin_amdgcn_s_setprio(1);
            a0 = __builtin_amdgcn_mfma_f32_32x32x16_f16(ah[k0], bh0a, a0, 0, 0, 0);
            a2 = __builtin_amdgcn_mfma_f32_32x32x16_f16(ah[k0], bh1a, a2, 0, 0, 0);
            a1 = __builtin_amdgcn_mfma_f32_32x32x16_f16(ah[k0], bl0a, a1, 0, 0, 0);
            a3 = __builtin_amdgcn_mfma_f32_32x32x16_f16(ah[k0], bl1a, a3, 0, 0, 0);
            a0 = __builtin_amdgcn_mfma_f32_32x32x16_f16(al[k0], bh0a, a0, 0, 0, 0);
            a2 = __builtin_amdgcn_mfma_f32_32x32x16_f16(al[k0], bh1a, a2, 0, 0, 0);
            a1 = __builtin_amdgcn_mfma_f32_32x32x16_f16(ah[k1], bl0b, a1, 0, 0, 0);
            a3 = __builtin_amdgcn_mfma_f32_32x32x16_f16(ah[k1], bl1b, a3, 0, 0, 0);
            a0 = __builtin_amdgcn_mfma_f32_32x32x16_f16(ah[k1], bh0b, a0, 0, 0, 0);
            a2 = __builtin_amdgcn_mfma_f32_32x32x16_f16(ah[k1], bh1b, a2, 0, 0, 0);
            a0 = __builtin_amdgcn_mfma_f32_32x32x16_f16(al[k1], bh0b, a0, 0, 0, 0);
            a2 = __builtin_amdgcn_mfma_f32_32x32x16_f16(al[k1], bh1b, a2, 0, 0, 0);
            __builtin_amdgcn_s_setprio(0);
            __builtin_amdgcn_s_barrier();
        }

        // fused scoring: s = 2*dot - e^2 ; codes ascend (n=0 then n=1), strict >
        const int code0 = ch * CH + lm;
        #pragma unroll
        for (int r = 0; r < 16; ++r) {
            float s0 = fmaf(2.f, a0[r] + a1[r], -eq0);
            float s1 = fmaf(2.f, a2[r] + a3[r], -eq1);
            if (s0 > best[r]) { best[r] = s0; bidx[r] = code0; }
            if (s1 > best[r]) { best[r] = s1; bidx[r] = code0 + 32; }
        }
    }

    // ---- cross-lane argmax over 32 code-lanes (ties -> lower index) ----
    #pragma unroll
    for (int r = 0; r < 16; ++r) {
        float bs = best[r]; int bi = bidx[r];
        #pragma unroll
        for (int m = 1; m <= 16; m <<= 1) {
            float vs = __shfl_xor(bs, m, 64);
            int   vi = __shfl_xor(bi, m, 64);
            if (vs > bs || (vs == bs && vi < bi)) { bs = vs; bi = vi; }
        }
        if (lm == 0) {
            int grow = wid * 32 + (r & 3) + 8 * (r >> 2) + 4 * lh;
            winners[grow] = bi;
            outi[row0 + grow] = (float)bi;
        }
    }
    __syncthreads();

    // ---- gather quantized = embed[winner] (exact fp32 copy) ----
    #pragma unroll
    for (int i = 0; i < 16; ++i) {
        int pos = i * THREADS + tid;
        int r = pos >> 5, c4 = pos & 31;
        int idx = winners[r];
        float4 v = ((const float4*)(embed + (size_t)idx * Cdim))[c4];
        ((float4*)(outq + (size_t)(row0 + r) * Cdim))[c4] = v;
    }
}

extern "C" void kernel_launch(void* const* d_in, const int* in_sizes, int n_in,
                              void* d_out, int out_size, void* d_ws, size_t ws_size,
                              hipStream_t stream) {
    const float* x     = (const float*)d_in[0];
    const float* embed = (const float*)d_in[1];
    const int M = in_sizes[0] / Cdim;   // 65536
    const int K = in_sizes[1] / Cdim;   // 1024
    float* outq = (float*)d_out;
    float* outi = outq + (size_t)M * Cdim;

    esq_kernel <<<K / 4, 256, 0, stream>>>(embed, (float*)d_ws, K);
    bconv_kernel<<<64,    256, 0, stream>>>(embed, (char*)d_ws);
    vq_kernel  <<<M / BROWS, THREADS, 0, stream>>>(x, embed, (const char*)d_ws,
                                                   outq, outi);
}

// Round 6
// 68.812 us; speedup vs baseline: 1.1445x; 1.1445x over previous
//
#include <hip/hip_runtime.h>
#include <float.h>

// EuclideanCodebook R6: operand-swapped f16-split MFMA (A=codebook, B=x).
// - 8 waves x 512thr, 1 block/CU; wave-pair (w, w+4) shares 64 x-rows, splits
//   the 64-code chunk in half -> e-fragments reused over 2 row-tiles (LDS:MFMA 1:2).
// - A=e makes C cols = x-rows: per-lane 16 accs = 16 codes of ONE row ->
//   argmax is lane-local (best/bidx scalars), epilogue reduce = 2 shuffles.
// - score = 2*dot(x,e) - e^2 folded entirely into MFMA via K-extension kstep:
//   e~[128,129] = f16split(-e^2), x~[128,129] = [1,1]. x^2 dropped (row-const).
// - dot via f16 split: (2xh)*eh + (2xh)*el + (2xl)*eh, fp32 accumulate.
// ws: [0: esq 4KB | 4096: kk8 frags 32KB | 36864: chunk frags 512KB]

#define Cdim        128
#define KCODES      1024
#define CH          64
#define NCH         16
#define BROWS       256       // 4 row-groups x 64 rows; wave pair per group
#define THREADS     512
#define KK8_OFF     4096
#define IMG_OFF     36864
#define CHUNK_BYTES 32768     // per chunk: [nt0 hi 8K | nt0 lo 8K | nt1 hi | nt1 lo]

typedef _Float16 f16;
typedef __attribute__((ext_vector_type(8)))  _Float16 f16x8;
typedef __attribute__((ext_vector_type(16))) float    f32x16;

// ---------------- e_sq pre-pass (exact fp32) ----------------
__global__ __launch_bounds__(256) void esq_kernel(const float* __restrict__ embed,
                                                  float* __restrict__ esq, int K) {
    int gid  = blockIdx.x * blockDim.x + threadIdx.x;
    int code = gid >> 6;
    int lane = threadIdx.x & 63;
    if (code >= K) return;
    float2 v = ((const float2*)(embed + (size_t)code * Cdim))[lane];
    float  s = fmaf(v.x, v.x, v.y * v.y);
    #pragma unroll
    for (int m = 32; m >= 1; m >>= 1) s += __shfl_xor(s, m, 64);
    if (lane == 0) esq[code] = s;
}

__device__ __forceinline__ void cvt8s(float4 a, float4 b, float scale,
                                      f16x8& h, f16x8& lo) {
    float v[8] = {a.x, a.y, a.z, a.w, b.x, b.y, b.z, b.w};
    #pragma unroll
    for (int i = 0; i < 8; ++i) {
        float s = v[i] * scale;
        f16 hh = (f16)s;
        h[i]  = hh;
        lo[i] = (f16)(s - (float)hh);
    }
}

// ---- codebook -> fragment-order image; one thread per (code, kk, lh) ----
// frag addr (kk<8):  IMG_OFF + ch*32768 + nt*16384 + kk*1024 + lh*512 + lm*16
//                    (lo plane at +8192)
// kk==8 (e^2 fold):  KK8_OFF + ch*2048 + nt*1024 + lh*512 + lm*16
__global__ __launch_bounds__(256) void bconv_kernel(const float* __restrict__ embed,
                                                    const float* __restrict__ esq,
                                                    char* __restrict__ ws) {
    int t    = blockIdx.x * 256 + threadIdx.x;   // 18432 threads
    int code = t / 18;
    int slot = t % 18;
    int kk   = slot >> 1;
    int lh   = slot & 1;
    int ch = code >> 6, nt = (code >> 5) & 1, lm = code & 31;
    if (kk < 8) {
        const float4* p = (const float4*)(embed + (size_t)code * Cdim + kk * 16 + lh * 8);
        f16x8 h, lo;
        cvt8s(p[0], p[1], 1.0f, h, lo);
        size_t base = (size_t)IMG_OFF + (size_t)ch * CHUNK_BYTES + nt * 16384
                    + kk * 1024 + lh * 512 + lm * 16;
        *(f16x8*)(ws + base)        = h;
        *(f16x8*)(ws + base + 8192) = lo;
    } else {
        f16x8 f = {};
        if (lh == 0) {
            float e2 = esq[code];
            f16 e2h = (f16)e2;
            f16 e2l = (f16)(e2 - (float)e2h);
            f[0] = -e2h; f[1] = -e2l;
        }
        size_t base = (size_t)KK8_OFF + (size_t)ch * 2048 + nt * 1024
                    + lh * 512 + lm * 16;
        *(f16x8*)(ws + base) = f;
    }
}

// ---------------- async global->LDS 16B ----------------
__device__ __forceinline__ void gll16(const void* g, void* l) {
    __builtin_amdgcn_global_load_lds(
        (const __attribute__((address_space(1))) unsigned int*)g,
        (__attribute__((address_space(3))) unsigned int*)l, 16, 0, 0);
}

__global__ __launch_bounds__(THREADS) void vq_kernel(
    const float* __restrict__ x, const float* __restrict__ embed,
    const char* __restrict__ ws, float* __restrict__ outq,
    float* __restrict__ outi) {

    __shared__ __align__(16) char  Bb[2][CHUNK_BYTES];   // 64KB dbuf
    __shared__ __align__(16) char  Kk8[32768];           // resident kk8 frags
    __shared__ float mrg_v[2][BROWS];
    __shared__ int   mrg_i[2][BROWS];
    __shared__ int   winners[BROWS];

    const int tid  = threadIdx.x;
    const int wid  = tid >> 6;
    const int l    = tid & 63;
    const int lm   = l & 31;
    const int lh   = l >> 5;
    const int nt   = wid >> 2;          // code half of each chunk
    const int wr   = wid & 3;           // row group (64 rows)
    const int row0 = blockIdx.x * BROWS;
    const int loff = lh * 512 + lm * 16;

    // ---- prologue DMA: chunk 0 + resident kk8 frags ----
    {
        const char* src0 = ws + IMG_OFF + wid * 4096 + (size_t)l * 16;
        char*       dst0 = &Bb[0][wid * 4096];
        #pragma unroll
        for (int i = 0; i < 4; ++i) gll16(src0 + i * 1024, dst0 + i * 1024);
        const char* src1 = ws + KK8_OFF + wid * 4096 + (size_t)l * 16;
        char*       dst1 = Kk8 + wid * 4096;
        #pragma unroll
        for (int i = 0; i < 4; ++i) gll16(src1 + i * 1024, dst1 + i * 1024);
    }

    // ---- x rows -> B-fragments (2*xh, 2*xl), 2 n-tiles of 32 rows ----
    f16x8 bxh[2][8], bxl[2][8];
    #pragma unroll
    for (int n = 0; n < 2; ++n) {
        const float* xr = x + (size_t)(row0 + wr * 64 + n * 32 + lm) * Cdim + lh * 8;
        #pragma unroll
        for (int kk = 0; kk < 8; ++kk) {
            float4 v0 = *(const float4*)(xr + kk * 16);
            float4 v1 = *(const float4*)(xr + kk * 16 + 4);
            cvt8s(v0, v1, 2.0f, bxh[n][kk], bxl[n][kk]);
        }
    }

    // x~ extension fragment: k=128,129 -> 1,1 (lh==0 lanes only)
    f16x8 bconst = {};
    if (lh == 0) { bconst[0] = (f16)1.f; bconst[1] = (f16)1.f; }

    float best0 = -FLT_MAX, best1 = -FLT_MAX;
    int   bidx0 = 0,        bidx1 = 0;

    asm volatile("s_waitcnt vmcnt(0)" ::: "memory");
    __builtin_amdgcn_s_barrier();

    #pragma unroll 1
    for (int ch = 0; ch < NCH; ++ch) {
        const int cur = ch & 1, nxt = cur ^ 1;

        __builtin_amdgcn_s_barrier();            // safe to overwrite Bb[nxt]
        if (ch + 1 < NCH) {                      // prefetch chunk ch+1
            const char* src = ws + IMG_OFF + (size_t)(ch + 1) * CHUNK_BYTES
                            + wid * 4096 + (size_t)l * 16;
            char* dst = &Bb[nxt][wid * 4096];
            #pragma unroll
            for (int i = 0; i < 4; ++i) gll16(src + i * 1024, dst + i * 1024);
            asm volatile("s_waitcnt vmcnt(4)" ::: "memory");   // chunk ch staged
        } else {
            asm volatile("s_waitcnt vmcnt(0)" ::: "memory");
        }
        __builtin_amdgcn_s_barrier();            // all waves' chunk ch visible

        f32x16 acc0, acc1;
        #pragma unroll
        for (int r = 0; r < 16; ++r) { acc0[r] = 0.f; acc1[r] = 0.f; }

        const char* bbA = &Bb[cur][nt * 16384 + loff];
        f16x8 ae8 = *(const f16x8*)(&Kk8[ch * 2048 + nt * 1024 + loff]);
        f16x8 aeh = *(const f16x8*)(bbA);
        f16x8 ael = *(const f16x8*)(bbA + 8192);

        #pragma unroll
        for (int kk = 0; kk < 8; ++kk) {
            f16x8 aehN, aelN;
            if (kk < 7) {
                aehN = *(const f16x8*)(bbA + (kk + 1) * 1024);
                aelN = *(const f16x8*)(bbA + 8192 + (kk + 1) * 1024);
            }
            acc0 = __builtin_amdgcn_mfma_f32_32x32x16_f16(aeh, bxh[0][kk], acc0, 0, 0, 0);
            acc1 = __builtin_amdgcn_mfma_f32_32x32x16_f16(aeh, bxh[1][kk], acc1, 0, 0, 0);
            acc0 = __builtin_amdgcn_mfma_f32_32x32x16_f16(ael, bxh[0][kk], acc0, 0, 0, 0);
            acc1 = __builtin_amdgcn_mfma_f32_32x32x16_f16(ael, bxh[1][kk], acc1, 0, 0, 0);
            acc0 = __builtin_amdgcn_mfma_f32_32x32x16_f16(aeh, bxl[0][kk], acc0, 0, 0, 0);
            acc1 = __builtin_amdgcn_mfma_f32_32x32x16_f16(aeh, bxl[1][kk], acc1, 0, 0, 0);
            aeh = aehN; ael = aelN;
        }
        acc0 = __builtin_amdgcn_mfma_f32_32x32x16_f16(ae8, bconst, acc0, 0, 0, 0);
        acc1 = __builtin_amdgcn_mfma_f32_32x32x16_f16(ae8, bconst, acc1, 0, 0, 0);

        // lane-local scoring: acc[r] = 2*dot - e^2 for code cb + rl(r), ascending
        const int cb = ch * CH + nt * 32 + lh * 4;
        #pragma unroll
        for (int r = 0; r < 16; ++r) {
            const int code = cb + (r & 3) + 8 * (r >> 2);
            float s0 = acc0[r], s1 = acc1[r];
            if (s0 > best0) { best0 = s0; bidx0 = code; }
            if (s1 > best1) { best1 = s1; bidx1 = code; }
        }
    }

    // ---- merge lh halves (codes interleave 4-blocks; index-aware) ----
    {
        float v; int vi;
        v = __shfl_xor(best0, 32, 64); vi = __shfl_xor(bidx0, 32, 64);
        if (v > best0 || (v == best0 && vi < bidx0)) { best0 = v; bidx0 = vi; }
        v = __shfl_xor(best1, 32, 64); vi = __shfl_xor(bidx1, 32, 64);
        if (v > best1 || (v == best1 && vi < bidx1)) { best1 = v; bidx1 = vi; }
    }
    // ---- wave-pair merge via LDS (code halves nt=0/1) ----
    if (lh == 0) {
        mrg_v[nt][wr * 64 + lm]      = best0;  mrg_i[nt][wr * 64 + lm]      = bidx0;
        mrg_v[nt][wr * 64 + 32 + lm] = best1;  mrg_i[nt][wr * 64 + 32 + lm] = bidx1;
    }
    __syncthreads();
    if (tid < BROWS) {
        float v0 = mrg_v[0][tid]; int i0 = mrg_i[0][tid];
        float v1 = mrg_v[1][tid]; int i1 = mrg_i[1][tid];
        int bi = (v1 > v0 || (v1 == v0 && i1 < i0)) ? i1 : i0;
        winners[tid] = bi;
        outi[row0 + tid] = (float)bi;
    }
    __syncthreads();

    // ---- gather quantized = embed[winner] (exact fp32 copy) ----
    #pragma unroll
    for (int i = 0; i < 16; ++i) {
        int pos = i * THREADS + tid;
        int r = pos >> 5, c4 = pos & 31;
        int idx = winners[r];
        float4 v = ((const float4*)(embed + (size_t)idx * Cdim))[c4];
        ((float4*)(outq + (size_t)(row0 + r) * Cdim))[c4] = v;
    }
}

extern "C" void kernel_launch(void* const* d_in, const int* in_sizes, int n_in,
                              void* d_out, int out_size, void* d_ws, size_t ws_size,
                              hipStream_t stream) {
    const float* x     = (const float*)d_in[0];
    const float* embed = (const float*)d_in[1];
    const int M = in_sizes[0] / Cdim;   // 65536
    const int K = in_sizes[1] / Cdim;   // 1024
    float* outq = (float*)d_out;
    float* outi = outq + (size_t)M * Cdim;

    esq_kernel <<<K / 4, 256, 0, stream>>>(embed, (float*)d_ws, K);
    bconv_kernel<<<72, 256, 0, stream>>>(embed, (const float*)d_ws, (char*)d_ws);
    vq_kernel  <<<M / BROWS, THREADS, 0, stream>>>(x, embed, (const char*)d_ws,
                                                   outq, outi);
}